// Round 12
// baseline (172.854 us; speedup 1.0000x reference)
//
#include <hip/hip_runtime.h>
#include <cstdint>
#include <cstddef>

#define SL 4096
#define DM 768

typedef short s16x8 __attribute__((ext_vector_type(8)));
typedef unsigned short u16x8 __attribute__((ext_vector_type(8)));
typedef unsigned short u16x4 __attribute__((ext_vector_type(4)));
typedef float f32x4 __attribute__((ext_vector_type(4)));
typedef float f32x16 __attribute__((ext_vector_type(16)));
typedef unsigned int u32x4 __attribute__((ext_vector_type(4)));

__device__ __forceinline__ unsigned short f2bf(float f) {
  unsigned u = __float_as_uint(f);
  u = u + 0x7fffu + ((u >> 16) & 1u);   // round-to-nearest-even
  return (unsigned short)(u >> 16);
}
__device__ __forceinline__ float bf2f(unsigned short v) {
  return __uint_as_float((unsigned)v << 16);
}

// 16B-block XOR swizzle within a 64-short (128B) row (guide G4/T2).
__device__ __forceinline__ int swz(int row, int col) {
  return (row << 6) + ((((col >> 3) ^ row) & 7) << 3) + (col & 7);
}

#define ASYNC16(G, L)                                                        \
  __builtin_amdgcn_global_load_lds(                                          \
      (const __attribute__((address_space(1))) void*)(G),                    \
      (__attribute__((address_space(3))) void*)(L), 16, 0, 0)

#define WAITB()                                   \
  do {                                            \
    asm volatile("s_waitcnt vmcnt(0)" ::: "memory"); \
    __builtin_amdgcn_s_barrier();                 \
  } while (0)

#define MF32(A, B, C) __builtin_amdgcn_mfma_f32_32x32x16_bf16((A), (B), (C), 0, 0, 0)

// ---- fused prep: x->bf16 cvt, W_attn^T, W_out^T, kmx zero ----
__device__ __forceinline__ void tr_body(
    const float* __restrict__ in, unsigned short* __restrict__ out,
    int R, int C, int bx, int by, float (*tile)[65], int t) {
  const int r0 = by * 64, c0 = bx * 64;
  const int lr = t >> 2, lcb = (t & 3) * 16;
  #pragma unroll
  for (int j = 0; j < 16; j += 4) {
    f32x4 v = *reinterpret_cast<const f32x4*>(in + (size_t)(r0 + lr) * C + c0 + lcb + j);
    tile[lr][lcb + j + 0] = v[0];
    tile[lr][lcb + j + 1] = v[1];
    tile[lr][lcb + j + 2] = v[2];
    tile[lr][lcb + j + 3] = v[3];
  }
  __syncthreads();
  #pragma unroll
  for (int j = 0; j < 16; j += 4) {
    u16x4 o;
    o[0] = f2bf(tile[lcb + j + 0][lr]);
    o[1] = f2bf(tile[lcb + j + 1][lr]);
    o[2] = f2bf(tile[lcb + j + 2][lr]);
    o[3] = f2bf(tile[lcb + j + 3][lr]);
    *reinterpret_cast<u16x4*>(out + (size_t)(c0 + lr) * R + r0 + lcb + j) = o;
  }
}

extern "C" __global__ __launch_bounds__(256) void k_prep(
    const float* __restrict__ x, const float* __restrict__ Wa,
    const float* __restrict__ Wo, unsigned short* __restrict__ xbf,
    unsigned short* __restrict__ wat, unsigned short* __restrict__ wot,
    unsigned* __restrict__ kmx) {
  __shared__ float tile[64][65];
  const int b = blockIdx.x, t = threadIdx.x;
  if (b < 3072) {
    if (b == 0 && t < 12) kmx[t] = 0u;
    const int i = (b * 256 + t) * 4;
    f32x4 v = *reinterpret_cast<const f32x4*>(x + i);
    u16x4 o;
    o[0] = f2bf(v[0]); o[1] = f2bf(v[1]); o[2] = f2bf(v[2]); o[3] = f2bf(v[3]);
    *reinterpret_cast<u16x4*>(xbf + i) = o;
  } else if (b < 3504) {
    const int bb = b - 3072;
    tr_body(Wa, wat, 768, 2304, bb % 36, bb / 36, tile, t);
  } else {
    const int bb = b - 3504;
    tr_body(Wo, wot, 768, 768, bb % 12, bb / 12, tile, t);
  }
}

// ---- QKV GEMM, 128x128 tile, BK=64, async dbuf; epilogue computes row norms ----
extern "C" __global__ __launch_bounds__(256) void k_qkv(
    const unsigned short* __restrict__ xbf, const unsigned short* __restrict__ wt,
    const float* __restrict__ bias, unsigned short* __restrict__ qb,
    unsigned short* __restrict__ kbo, unsigned short* __restrict__ vtb,
    float* __restrict__ qn2, unsigned* __restrict__ kmx) {
  __shared__ alignas(16) unsigned short a_lds[2][8192];
  __shared__ alignas(16) unsigned short b_lds[2][8192];
  const int t = threadIdx.x, w = t >> 6, l = t & 63;
  const int l15 = l & 15, lg = l >> 4;
  const int wr = w >> 1, wc = w & 1;
  const int n0 = blockIdx.x * 128, m0 = blockIdx.y * 128;
  f32x4 acc[4][4];
  #pragma unroll
  for (int mt = 0; mt < 4; mt++)
    #pragma unroll
    for (int nt = 0; nt < 4; nt++) acc[mt][nt] = (f32x4)0.f;
  int soff[4];
  #pragma unroll
  for (int c = 0; c < 4; c++) {
    int i = c * 256 + t;
    int row = i >> 3, bp = i & 7;
    soff[c] = row * DM + (bp ^ (row & 7)) * 8;
  }
  const unsigned short* asrc = xbf + (size_t)m0 * DM;
  const unsigned short* bsrc = wt + (size_t)n0 * DM;

#define STAGE128(B, KK)                                                   \
  do {                                                                    \
    _Pragma("unroll")                                                     \
    for (int c = 0; c < 4; c++) {                                         \
      ASYNC16(asrc + (KK) + soff[c], &a_lds[B][0] + c * 2048 + w * 512);  \
      ASYNC16(bsrc + (KK) + soff[c], &b_lds[B][0] + c * 2048 + w * 512);  \
    }                                                                     \
  } while (0)

#define GEMM128(B)                                                            \
  do {                                                                        \
    _Pragma("unroll")                                                         \
    for (int kc = 0; kc < 2; kc++) {                                          \
      s16x8 af[4], bfv[4];                                                    \
      _Pragma("unroll")                                                       \
      for (int mt = 0; mt < 4; mt++)                                          \
        af[mt] = *reinterpret_cast<const s16x8*>(                             \
            &a_lds[B][swz(wr * 64 + mt * 16 + l15, kc * 32 + lg * 8)]);       \
      _Pragma("unroll")                                                       \
      for (int nt = 0; nt < 4; nt++)                                          \
        bfv[nt] = *reinterpret_cast<const s16x8*>(                            \
            &b_lds[B][swz(wc * 64 + nt * 16 + l15, kc * 32 + lg * 8)]);       \
      _Pragma("unroll")                                                       \
      for (int mt = 0; mt < 4; mt++)                                          \
        _Pragma("unroll")                                                     \
        for (int nt = 0; nt < 4; nt++)                                        \
          acc[mt][nt] = __builtin_amdgcn_mfma_f32_16x16x32_bf16(              \
              af[mt], bfv[nt], acc[mt][nt], 0, 0, 0);                         \
    }                                                                         \
  } while (0)

  STAGE128(0, 0);
  WAITB();
  #pragma unroll 1
  for (int kk = 0; kk < DM; kk += 128) {
    STAGE128(1, kk + 64);
    GEMM128(0);
    WAITB();
    if (kk + 128 < DM) STAGE128(0, kk + 128);
    GEMM128(1);
    WAITB();
  }
#undef STAGE128
#undef GEMM128

  const int secn = (n0 >= 1536) ? 2 : (n0 >= 768 ? 1 : 0);
  const int nbase = n0 - secn * 768 + wc * 64;   // 64-aligned within section
  const int h = nbase >> 6;                      // this wave's head
  const int mrow0 = m0 + wr * 64;
  float bv4[4];
  #pragma unroll
  for (int nt = 0; nt < 4; nt++) bv4[nt] = bias[secn * 768 + nbase + nt * 16 + l15];

  if (secn == 0) {
    const float QS = 0.180336880f;               // 0.125*log2(e)
    float s2[4][4];
    #pragma unroll
    for (int mt = 0; mt < 4; mt++) {
      #pragma unroll
      for (int r = 0; r < 4; r++) s2[mt][r] = 0.f;
    }
    #pragma unroll
    for (int mt = 0; mt < 4; mt++) {
      #pragma unroll
      for (int nt = 0; nt < 4; nt++) {
        const int d = nt * 16 + l15;
        #pragma unroll
        for (int r = 0; r < 4; r++) {
          const int m = mrow0 + mt * 16 + lg * 4 + r;
          float v = (acc[mt][nt][r] + bv4[nt]) * QS;
          qb[((size_t)h * SL + m) * 64 + d] = f2bf(v);
          s2[mt][r] = fmaf(v, v, s2[mt][r]);
        }
      }
    }
    #pragma unroll
    for (int mt = 0; mt < 4; mt++)
      #pragma unroll
      for (int r = 0; r < 4; r++) {
        #pragma unroll
        for (int off = 1; off < 16; off <<= 1)
          s2[mt][r] += __shfl_xor(s2[mt][r], off, 64);
      }
    if (l15 == 0) {
      #pragma unroll
      for (int mt = 0; mt < 4; mt++)
        #pragma unroll
        for (int r = 0; r < 4; r++)
          qn2[(size_t)h * SL + mrow0 + mt * 16 + lg * 4 + r] = s2[mt][r];
    }
  } else if (secn == 1) {
    float s2[4][4];
    #pragma unroll
    for (int mt = 0; mt < 4; mt++) {
      #pragma unroll
      for (int r = 0; r < 4; r++) s2[mt][r] = 0.f;
    }
    #pragma unroll
    for (int mt = 0; mt < 4; mt++) {
      #pragma unroll
      for (int nt = 0; nt < 4; nt++) {
        const int d = nt * 16 + l15;
        #pragma unroll
        for (int r = 0; r < 4; r++) {
          const int m = mrow0 + mt * 16 + lg * 4 + r;
          float v = acc[mt][nt][r] + bv4[nt];
          kbo[((size_t)h * SL + m) * 64 + d] = f2bf(v);
          s2[mt][r] = fmaf(v, v, s2[mt][r]);
        }
      }
    }
    float rm = 0.f;
    #pragma unroll
    for (int mt = 0; mt < 4; mt++)
      #pragma unroll
      for (int r = 0; r < 4; r++) {
        #pragma unroll
        for (int off = 1; off < 16; off <<= 1)
          s2[mt][r] += __shfl_xor(s2[mt][r], off, 64);
        rm = fmaxf(rm, s2[mt][r]);
      }
    rm = fmaxf(rm, __shfl_xor(rm, 16, 64));
    rm = fmaxf(rm, __shfl_xor(rm, 32, 64));
    if (l == 0) atomicMax(kmx + h, __float_as_uint(rm));   // norm^2, >=0
  } else {
    #pragma unroll
    for (int mt = 0; mt < 4; mt++) {
      #pragma unroll
      for (int nt = 0; nt < 4; nt++) {
        const int d = nt * 16 + l15;
        u16x4 o;
        #pragma unroll
        for (int r = 0; r < 4; r++) o[r] = f2bf(acc[mt][nt][r] + bv4[nt]);
        *reinterpret_cast<u16x4*>(
            vtb + ((size_t)h * 64 + d) * SL + mrow0 + mt * 16 + lg * 4) = o;
      }
    }
  }
}

// 32x32 swapped attention body, KVBLK=32, fixed-bound softmax (-M via MFMA),
// row-sum via MFMA ones-trick. kfo/vfo are precomputed conflict-free offsets.
__device__ __forceinline__ void attn_body32f(
    const unsigned short* kb, const unsigned short* vb,
    const s16x8* qf, f32x16* ot, f32x16& lacc, s16x8 qm,
    const int* kfo, const int* vfo, s16x8 ones) {
  f32x16 st = (f32x16)0.f;
  __builtin_amdgcn_s_setprio(1);
  #pragma unroll
  for (int c = 0; c < 4; c++) {
    s16x8 kf = *reinterpret_cast<const s16x8*>(&kb[kfo[c]]);
    st = MF32(kf, qf[c], st);
  }
  st = MF32(ones, qm, st);
  __builtin_amdgcn_s_setprio(0);
  #pragma unroll
  for (int r = 0; r < 16; r++) st[r] = exp2f(st[r]);
  #pragma unroll
  for (int m = 0; m < 2; m++) {
    const int m0 = m * 8;
    unsigned w0, w1, w2, w3;
    asm("v_cvt_pk_bf16_f32 %0, %1, %2" : "=v"(w0) : "v"(st[m0 + 0]), "v"(st[m0 + 1]));
    asm("v_cvt_pk_bf16_f32 %0, %1, %2" : "=v"(w1) : "v"(st[m0 + 2]), "v"(st[m0 + 3]));
    asm("v_cvt_pk_bf16_f32 %0, %1, %2" : "=v"(w2) : "v"(st[m0 + 4]), "v"(st[m0 + 5]));
    asm("v_cvt_pk_bf16_f32 %0, %1, %2" : "=v"(w3) : "v"(st[m0 + 6]), "v"(st[m0 + 7]));
    asm volatile("v_permlane32_swap_b32 %0, %1" : "+v"(w0), "+v"(w2));
    asm volatile("v_permlane32_swap_b32 %0, %1" : "+v"(w1), "+v"(w3));
    u32x4 wv_;
    wv_[0] = w0; wv_[1] = w1; wv_[2] = w2; wv_[3] = w3;
    s16x8 pbf = *reinterpret_cast<s16x8*>(&wv_);
    __builtin_amdgcn_s_setprio(1);
    #pragma unroll
    for (int dt = 0; dt < 2; dt++) {
      s16x8 vf = *reinterpret_cast<const s16x8*>(&vb[vfo[m * 2 + dt]]);
      ot[dt] = MF32(vf, pbf, ot[dt]);
    }
    lacc = MF32(ones, pbf, lacc);
    __builtin_amdgcn_s_setprio(0);
  }
}

// Flash attention, FINE GRID: 1536 WGs = 12 h x 64 qtile x 2 KV-halves.
// WG = 4 waves = 2 q-subtiles x 2 KV-quarters (1024 keys/wave), KVBLK=32,
// counted vmcnt(4), conflict-free fused V tile. Fixed-M softmax makes partials
// additive: WG merges its 2 quarters in LDS, writes UNNORMALIZED partial O
// (bf16) + partial l per half; k_norm combines halves (no atomics).
extern "C" __global__ __launch_bounds__(256) void k_attn(
    const unsigned short* __restrict__ qb, const unsigned short* __restrict__ kbi,
    const unsigned short* __restrict__ vt, const float* __restrict__ qn2,
    const unsigned* __restrict__ kmx, unsigned short* __restrict__ obuf,
    float* __restrict__ lbuf) {
  __shared__ alignas(16) unsigned char smem[32768];
  unsigned short* kst = (unsigned short*)smem;             // [4][2048] K staging
  unsigned short* vst = (unsigned short*)(smem + 16384);   // [4][2048] V staging
  const int t = threadIdx.x, w = t >> 6, l = t & 63;
  const int l31 = l & 31, s = l >> 5;
  const int sub = w >> 1, qs = w & 1;            // sub = KV quarter within half
  const int bid = blockIdx.x;
  const int sid = (bid & 7) * 192 + (bid >> 3);  // XCD clustering (bijective, 1536)
  const int h = sid >> 7;                        // 128 sids per head
  const int rem = sid & 127;
  const int qt = rem >> 1, half = rem & 1;
  const unsigned short* qh = qb + (size_t)h * SL * 64;
  const int kvbase = half * 2048 + sub * 1024;
  const unsigned short* kh = kbi + ((size_t)h * SL + kvbase) * 64;
  const unsigned short* vh = vt + (size_t)h * 64 * SL + kvbase;
  const int q = qt * 64 + qs * 32 + l31;
  const float M = sqrtf(qn2[(size_t)h * SL + q] * __uint_as_float(kmx[h]));
  s16x8 qf[4];
  #pragma unroll
  for (int c = 0; c < 4; c++)
    qf[c] = *reinterpret_cast<const s16x8*>(qh + (size_t)q * 64 + c * 16 + s * 8);
  s16x8 ones;
  #pragma unroll
  for (int e = 0; e < 8; e++) ones[e] = (short)0x3F80;     // bf16 1.0
  s16x8 qm = (s16x8)0;
  if (s == 0) qm[0] = (short)f2bf(-M);                      // k-slot 0 holds -M(q)
  f32x16 ot[2];
  ot[0] = (f32x16)0.f;
  ot[1] = (f32x16)0.f;
  f32x16 lacc = (f32x16)0.f;
  // staging source offsets (pre-inverse-swizzled; LDS dest linear) — R10-verified
  int koff[2], voff[2];
  #pragma unroll
  for (int c = 0; c < 2; c++) {
    int i = (qs * 2 + c) * 64 + l;
    int row = i >> 3, sb = i & 7;
    int bp = sb ^ ((row ^ (row >> 3)) & 7);
    koff[c] = row * 64 + bp * 8;
    int d = row + 32 * (bp >> 2);
    voff[c] = d * SL + (bp & 3) * 8;
  }
  // fragment read offsets (conflict-free, R9/R10-verified)
  const int sr = (l31 ^ (l31 >> 3)) & 7;
  int kfo[4], vfo[4];
  #pragma unroll
  for (int c = 0; c < 4; c++) kfo[c] = (l31 << 6) + (((c * 2 + s) ^ sr) << 3);
  #pragma unroll
  for (int m = 0; m < 2; m++)
    #pragma unroll
    for (int dt = 0; dt < 2; dt++)
      vfo[m * 2 + dt] = (l31 << 6) + (((dt * 4 + m * 2 + s) ^ sr) << 3);

#define STAGE_KV(B, LB)                                                     \
  do {                                                                      \
    _Pragma("unroll")                                                       \
    for (int c = 0; c < 2; c++) {                                           \
      ASYNC16(kh + (size_t)(LB) * 64 + koff[c],                             \
              kst + (sub * 2 + (B)) * 2048 + (qs * 2 + c) * 512);           \
      ASYNC16(vh + (LB) + voff[c],                                          \
              vst + (sub * 2 + (B)) * 2048 + (qs * 2 + c) * 512);           \
    }                                                                       \
  } while (0)

  STAGE_KV(0, 0);
  #pragma unroll 1
  for (int lb = 0; lb < 1024; lb += 64) {
    STAGE_KV(1, lb + 32);
    asm volatile("s_waitcnt vmcnt(4)" ::: "memory");   // buf0's 4 done; buf1 in flight
    __builtin_amdgcn_s_barrier();
    attn_body32f(kst + (sub * 2) * 2048, vst + (sub * 2) * 2048,
                 qf, ot, lacc, qm, kfo, vfo, ones);
    if (lb + 64 < 1024) {
      STAGE_KV(0, lb + 64);
      asm volatile("s_waitcnt vmcnt(4)" ::: "memory"); // buf1's 4 done; buf0 in flight
    } else {
      asm volatile("s_waitcnt vmcnt(0)" ::: "memory"); // tail drain
    }
    __builtin_amdgcn_s_barrier();
    attn_body32f(kst + (sub * 2 + 1) * 2048, vst + (sub * 2 + 1) * 2048,
                 qf, ot, lacc, qm, kfo, vfo, ones);
  }
#undef STAGE_KV
  // merge the two quarters (same M shift => plain adds); overlay staging LDS
  const float lsum = lacc[0];
  float* o_m = (float*)smem;                 // [2][32][68]
  float* l_m = (float*)(smem + 17408);       // [2][32]
  __syncthreads();
  if (sub == 1) {
    #pragma unroll
    for (int dt = 0; dt < 2; dt++) {
      #pragma unroll
      for (int rq = 0; rq < 4; rq++) {
        f32x4 v;
        #pragma unroll
        for (int j = 0; j < 4; j++) v[j] = ot[dt][rq * 4 + j];
        *reinterpret_cast<f32x4*>(&o_m[(qs * 32 + l31) * 68 + dt * 32 + rq * 8 + s * 4]) = v;
      }
    }
    if (s == 0) l_m[qs * 32 + l31] = lsum;
  }
  __syncthreads();
  if (sub == 0) {
    const float ltot = lsum + l_m[qs * 32 + l31];
    unsigned short* od = obuf + (size_t)half * SL * DM;
    #pragma unroll
    for (int dt = 0; dt < 2; dt++) {
      #pragma unroll
      for (int rq = 0; rq < 4; rq++) {
        f32x4 vb_ = *reinterpret_cast<const f32x4*>(&o_m[(qs * 32 + l31) * 68 + dt * 32 + rq * 8 + s * 4]);
        u16x4 o;
        #pragma unroll
        for (int j = 0; j < 4; j++)
          o[j] = f2bf(ot[dt][rq * 4 + j] + vb_[j]);       // UNNORMALIZED partial
        *reinterpret_cast<u16x4*>(od + (size_t)q * DM + h * 64 + dt * 32 + rq * 8 + s * 4) = o;
      }
    }
    if (s == 0) lbuf[half * 49152 + h * SL + q] = ltot;
  }
}

// combine the two KV-half partials and normalize: aob = (o0+o1)/(l0+l1)
extern "C" __global__ __launch_bounds__(256) void k_norm(
    const unsigned short* __restrict__ obuf, const float* __restrict__ lbuf,
    unsigned short* __restrict__ aob) {
  const int idx = blockIdx.x * 256 + threadIdx.x;   // one u16x4 per thread
  const int row = idx / 192, c4 = idx % 192;        // 192 = 768/4
  const int h = c4 >> 4;                             // 16 vec4-groups per head col-block
  const float li = 1.f / (lbuf[h * SL + row] + lbuf[49152 + h * SL + row]);
  u16x4 a = *reinterpret_cast<const u16x4*>(obuf + (size_t)idx * 4);
  u16x4 b = *reinterpret_cast<const u16x4*>(obuf + (size_t)SL * DM + (size_t)idx * 4);
  u16x4 o;
  #pragma unroll
  for (int j = 0; j < 4; j++) o[j] = f2bf((bf2f(a[j]) + bf2f(b[j])) * li);
  *reinterpret_cast<u16x4*>(aob + (size_t)idx * 4) = o;
}

// ---- out-proj GEMM + bias + residual -> y (fp32), 128x128 tile, async dbuf ----
extern "C" __global__ __launch_bounds__(256) void k_out(
    const unsigned short* __restrict__ abf, const unsigned short* __restrict__ wot,
    const float* __restrict__ bias, const float* __restrict__ x, float* __restrict__ y) {
  __shared__ alignas(16) unsigned short a_lds[2][8192];
  __shared__ alignas(16) unsigned short b_lds[2][8192];
  const int t = threadIdx.x, w = t >> 6, l = t & 63;
  const int l15 = l & 15, lg = l >> 4;
  const int wr = w >> 1, wc = w & 1;
  const int n0 = blockIdx.x * 128, m0 = blockIdx.y * 128;
  f32x4 acc[4][4];
  #pragma unroll
  for (int mt = 0; mt < 4; mt++)
    #pragma unroll
    for (int nt = 0; nt < 4; nt++) acc[mt][nt] = (f32x4)0.f;
  int soff[4];
  #pragma unroll
  for (int c = 0; c < 4; c++) {
    int i = c * 256 + t;
    int row = i >> 3, bp = i & 7;
    soff[c] = row * DM + (bp ^ (row & 7)) * 8;
  }
  const unsigned short* asrc = abf + (size_t)m0 * DM;
  const unsigned short* bsrc = wot + (size_t)n0 * DM;

#define STAGE128(B, KK)                                                   \
  do {                                                                    \
    _Pragma("unroll")                                                     \
    for (int c = 0; c < 4; c++) {                                         \
      ASYNC16(asrc + (KK) + soff[c], &a_lds[B][0] + c * 2048 + w * 512);  \
      ASYNC16(bsrc + (KK) + soff[c], &b_lds[B][0] + c * 2048 + w * 512);  \
    }                                                                     \
  } while (0)

#define GEMM128(B)                                                            \
  do {                                                                        \
    _Pragma("unroll")                                                         \
    for (int kc = 0; kc < 2; kc++) {                                          \
      s16x8 af[4], bfv[4];                                                    \
      _Pragma("unroll")                                                       \
      for (int mt = 0; mt < 4; mt++)                                          \
        af[mt] = *reinterpret_cast<const s16x8*>(                             \
            &a_lds[B][swz(wr * 64 + mt * 16 + l15, kc * 32 + lg * 8)]);       \
      _Pragma("unroll")                                                       \
      for (int nt = 0; nt < 4; nt++)                                          \
        bfv[nt] = *reinterpret_cast<const s16x8*>(                            \
            &b_lds[B][swz(wc * 64 + nt * 16 + l15, kc * 32 + lg * 8)]);       \
      _Pragma("unroll")                                                       \
      for (int mt = 0; mt < 4; mt++)                                          \
        _Pragma("unroll")                                                     \
        for (int nt = 0; nt < 4; nt++)                                        \
          acc[mt][nt] = __builtin_amdgcn_mfma_f32_16x16x32_bf16(              \
              af[mt], bfv[nt], acc[mt][nt], 0, 0, 0);                         \
    }                                                                         \
  } while (0)

  STAGE128(0, 0);
  WAITB();
  #pragma unroll 1
  for (int kk = 0; kk < DM; kk += 128) {
    STAGE128(1, kk + 64);
    GEMM128(0);
    WAITB();
    if (kk + 128 < DM) STAGE128(0, kk + 128);
    GEMM128(1);
    WAITB();
  }
#undef STAGE128
#undef GEMM128

  const int mrow0 = m0 + wr * 64;
  #pragma unroll
  for (int nt = 0; nt < 4; nt++) {
    const int n = n0 + wc * 64 + nt * 16 + l15;
    const float bv = bias[n];
    #pragma unroll
    for (int mt = 0; mt < 4; mt++) {
      #pragma unroll
      for (int r = 0; r < 4; r++) {
        const int m = mrow0 + mt * 16 + lg * 4 + r;
        y[(size_t)m * DM + n] = acc[mt][nt][r] + bv + x[(size_t)m * DM + n];
      }
    }
  }
}

extern "C" __global__ __launch_bounds__(256) void k_ln(
    const float* __restrict__ y, const float* __restrict__ g, const float* __restrict__ b,
    float* __restrict__ out) {
  const int row = blockIdx.x, t = threadIdx.x;
  const float* yr = y + (size_t)row * DM;
  float v0 = yr[t], v1 = yr[t + 256], v2 = yr[t + 512];
  float sum = v0 + v1 + v2;
  float sq = v0 * v0 + v1 * v1 + v2 * v2;
  #pragma unroll
  for (int off = 1; off < 64; off <<= 1) {
    sum += __shfl_xor(sum, off, 64);
    sq += __shfl_xor(sq, off, 64);
  }
  __shared__ float ls[8];
  const int wv = t >> 6, l = t & 63;
  if (l == 0) { ls[wv] = sum; ls[4 + wv] = sq; }
  __syncthreads();
  sum = ls[0] + ls[1] + ls[2] + ls[3];
  sq = ls[4] + ls[5] + ls[6] + ls[7];
  const float mu = sum * (1.f / DM);
  const float rstd = rsqrtf(sq * (1.f / DM) - mu * mu + 1e-5f);
  out[(size_t)row * DM + t] = (v0 - mu) * rstd * g[t] + b[t];
  out[(size_t)row * DM + t + 256] = (v1 - mu) * rstd * g[t + 256] + b[t + 256];
  out[(size_t)row * DM + t + 512] = (v2 - mu) * rstd * g[t + 512] + b[t + 512];
}

extern "C" void kernel_launch(void* const* d_in, const int* in_sizes, int n_in,
                              void* d_out, int out_size, void* d_ws, size_t ws_size,
                              hipStream_t stream) {
  (void)in_sizes; (void)n_in; (void)out_size; (void)ws_size;
  const float* x = (const float*)d_in[0];
  const float* Wa = (const float*)d_in[1];
  const float* ba = (const float*)d_in[2];
  const float* Wo = (const float*)d_in[3];
  const float* bo = (const float*)d_in[4];
  const float* lng = (const float*)d_in[5];
  const float* lnb = (const float*)d_in[6];
  float* out = (float*)d_out;

  unsigned short* ws16 = (unsigned short*)d_ws;
  unsigned short* xbf = ws16;                 // 4096x768
  unsigned short* wat = xbf + 3145728;        // 2304x768 (W_attn^T)
  unsigned short* wot = wat + 1769472;        // 768x768  (W_out^T)
  unsigned short* qbf = wot + 589824;         // [12][4096][64]
  unsigned short* kbf = qbf + 3145728;        // [12][4096][64]
  unsigned short* vtb = kbf + 3145728;        // [12][64][4096]
  unsigned short* aob = vtb + 3145728;        // 4096x768 attn out (normalized)
  float* ybuf = (float*)(aob + 3145728);      // 4096x768 fp32
  float* qn2 = ybuf + 3145728;                // [12][4096] |q|^2
  unsigned* kmx = (unsigned*)(qn2 + 49152);   // [12] max |k|^2 (as uint)
  float* lbuf = (float*)(kmx + 16);           // [2][12][4096] partial l
  unsigned short* obuf = (unsigned short*)(lbuf + 98304);  // [2][4096][768] partial O

  k_prep<<<3648, 256, 0, stream>>>(x, Wa, Wo, xbf, wat, wot, kmx);
  k_qkv<<<dim3(18, 32), 256, 0, stream>>>(xbf, wat, ba, qbf, kbf, vtb, qn2, kmx);
  k_attn<<<1536, 256, 0, stream>>>(qbf, kbf, vtb, qn2, kmx, obuf, lbuf);
  k_norm<<<3072, 256, 0, stream>>>(obuf, lbuf, aob);
  k_out<<<dim3(6, 32), 256, 0, stream>>>(aob, wot, bo, x, ybuf);
  k_ln<<<4096, 256, 0, stream>>>(ybuf, lng, lnb, out);
}

// Round 13
// 164.709 us; speedup vs baseline: 1.0495x; 1.0495x over previous
//
#include <hip/hip_runtime.h>
#include <cstdint>
#include <cstddef>

#define SL 4096
#define DM 768

typedef short s16x8 __attribute__((ext_vector_type(8)));
typedef unsigned short u16x8 __attribute__((ext_vector_type(8)));
typedef unsigned short u16x4 __attribute__((ext_vector_type(4)));
typedef float f32x4 __attribute__((ext_vector_type(4)));
typedef float f32x16 __attribute__((ext_vector_type(16)));
typedef unsigned int u32x4 __attribute__((ext_vector_type(4)));

__device__ __forceinline__ unsigned short f2bf(float f) {
  unsigned u = __float_as_uint(f);
  u = u + 0x7fffu + ((u >> 16) & 1u);   // round-to-nearest-even
  return (unsigned short)(u >> 16);
}

// 16B-block XOR swizzle within a 64-short (128B) row (guide G4/T2).
__device__ __forceinline__ int swz(int row, int col) {
  return (row << 6) + ((((col >> 3) ^ row) & 7) << 3) + (col & 7);
}

#define ASYNC16(G, L)                                                        \
  __builtin_amdgcn_global_load_lds(                                          \
      (const __attribute__((address_space(1))) void*)(G),                    \
      (__attribute__((address_space(3))) void*)(L), 16, 0, 0)

#define WAITB()                                   \
  do {                                            \
    asm volatile("s_waitcnt vmcnt(0)" ::: "memory"); \
    __builtin_amdgcn_s_barrier();                 \
  } while (0)

#define MF32(A, B, C) __builtin_amdgcn_mfma_f32_32x32x16_bf16((A), (B), (C), 0, 0, 0)

// ---- fused prep: x->bf16 cvt, W_attn^T, W_out^T, kmx zero ----
__device__ __forceinline__ void tr_body(
    const float* __restrict__ in, unsigned short* __restrict__ out,
    int R, int C, int bx, int by, float (*tile)[65], int t) {
  const int r0 = by * 64, c0 = bx * 64;
  const int lr = t >> 2, lcb = (t & 3) * 16;
  #pragma unroll
  for (int j = 0; j < 16; j += 4) {
    f32x4 v = *reinterpret_cast<const f32x4*>(in + (size_t)(r0 + lr) * C + c0 + lcb + j);
    tile[lr][lcb + j + 0] = v[0];
    tile[lr][lcb + j + 1] = v[1];
    tile[lr][lcb + j + 2] = v[2];
    tile[lr][lcb + j + 3] = v[3];
  }
  __syncthreads();
  #pragma unroll
  for (int j = 0; j < 16; j += 4) {
    u16x4 o;
    o[0] = f2bf(tile[lcb + j + 0][lr]);
    o[1] = f2bf(tile[lcb + j + 1][lr]);
    o[2] = f2bf(tile[lcb + j + 2][lr]);
    o[3] = f2bf(tile[lcb + j + 3][lr]);
    *reinterpret_cast<u16x4*>(out + (size_t)(c0 + lr) * R + r0 + lcb + j) = o;
  }
}

extern "C" __global__ __launch_bounds__(256) void k_prep(
    const float* __restrict__ x, const float* __restrict__ Wa,
    const float* __restrict__ Wo, unsigned short* __restrict__ xbf,
    unsigned short* __restrict__ wat, unsigned short* __restrict__ wot,
    unsigned* __restrict__ kmx) {
  __shared__ float tile[64][65];
  const int b = blockIdx.x, t = threadIdx.x;
  if (b < 3072) {
    if (b == 0 && t < 12) kmx[t] = 0u;
    const int i = (b * 256 + t) * 4;
    f32x4 v = *reinterpret_cast<const f32x4*>(x + i);
    u16x4 o;
    o[0] = f2bf(v[0]); o[1] = f2bf(v[1]); o[2] = f2bf(v[2]); o[3] = f2bf(v[3]);
    *reinterpret_cast<u16x4*>(xbf + i) = o;
  } else if (b < 3504) {
    const int bb = b - 3072;
    tr_body(Wa, wat, 768, 2304, bb % 36, bb / 36, tile, t);
  } else {
    const int bb = b - 3504;
    tr_body(Wo, wot, 768, 768, bb % 12, bb / 12, tile, t);
  }
}

// ---- QKV GEMM, 128x128 tile, BK=64, async dbuf; epilogue computes row norms ----
extern "C" __global__ __launch_bounds__(256) void k_qkv(
    const unsigned short* __restrict__ xbf, const unsigned short* __restrict__ wt,
    const float* __restrict__ bias, unsigned short* __restrict__ qb,
    unsigned short* __restrict__ kbo, unsigned short* __restrict__ vtb,
    float* __restrict__ qn2, unsigned* __restrict__ kmx) {
  __shared__ alignas(16) unsigned short a_lds[2][8192];
  __shared__ alignas(16) unsigned short b_lds[2][8192];
  const int t = threadIdx.x, w = t >> 6, l = t & 63;
  const int l15 = l & 15, lg = l >> 4;
  const int wr = w >> 1, wc = w & 1;
  const int n0 = blockIdx.x * 128, m0 = blockIdx.y * 128;
  f32x4 acc[4][4];
  #pragma unroll
  for (int mt = 0; mt < 4; mt++)
    #pragma unroll
    for (int nt = 0; nt < 4; nt++) acc[mt][nt] = (f32x4)0.f;
  int soff[4];
  #pragma unroll
  for (int c = 0; c < 4; c++) {
    int i = c * 256 + t;
    int row = i >> 3, bp = i & 7;
    soff[c] = row * DM + (bp ^ (row & 7)) * 8;
  }
  const unsigned short* asrc = xbf + (size_t)m0 * DM;
  const unsigned short* bsrc = wt + (size_t)n0 * DM;

#define STAGE128(B, KK)                                                   \
  do {                                                                    \
    _Pragma("unroll")                                                     \
    for (int c = 0; c < 4; c++) {                                         \
      ASYNC16(asrc + (KK) + soff[c], &a_lds[B][0] + c * 2048 + w * 512);  \
      ASYNC16(bsrc + (KK) + soff[c], &b_lds[B][0] + c * 2048 + w * 512);  \
    }                                                                     \
  } while (0)

#define GEMM128(B)                                                            \
  do {                                                                        \
    _Pragma("unroll")                                                         \
    for (int kc = 0; kc < 2; kc++) {                                          \
      s16x8 af[4], bfv[4];                                                    \
      _Pragma("unroll")                                                       \
      for (int mt = 0; mt < 4; mt++)                                          \
        af[mt] = *reinterpret_cast<const s16x8*>(                             \
            &a_lds[B][swz(wr * 64 + mt * 16 + l15, kc * 32 + lg * 8)]);       \
      _Pragma("unroll")                                                       \
      for (int nt = 0; nt < 4; nt++)                                          \
        bfv[nt] = *reinterpret_cast<const s16x8*>(                            \
            &b_lds[B][swz(wc * 64 + nt * 16 + l15, kc * 32 + lg * 8)]);       \
      _Pragma("unroll")                                                       \
      for (int mt = 0; mt < 4; mt++)                                          \
        _Pragma("unroll")                                                     \
        for (int nt = 0; nt < 4; nt++)                                        \
          acc[mt][nt] = __builtin_amdgcn_mfma_f32_16x16x32_bf16(              \
              af[mt], bfv[nt], acc[mt][nt], 0, 0, 0);                         \
    }                                                                         \
  } while (0)

  STAGE128(0, 0);
  WAITB();
  #pragma unroll 1
  for (int kk = 0; kk < DM; kk += 128) {
    STAGE128(1, kk + 64);
    GEMM128(0);
    WAITB();
    if (kk + 128 < DM) STAGE128(0, kk + 128);
    GEMM128(1);
    WAITB();
  }
#undef STAGE128
#undef GEMM128

  const int secn = (n0 >= 1536) ? 2 : (n0 >= 768 ? 1 : 0);
  const int nbase = n0 - secn * 768 + wc * 64;   // 64-aligned within section
  const int h = nbase >> 6;                      // this wave's head
  const int mrow0 = m0 + wr * 64;
  float bv4[4];
  #pragma unroll
  for (int nt = 0; nt < 4; nt++) bv4[nt] = bias[secn * 768 + nbase + nt * 16 + l15];

  if (secn == 0) {
    const float QS = 0.180336880f;               // 0.125*log2(e)
    float s2[4][4];
    #pragma unroll
    for (int mt = 0; mt < 4; mt++) {
      #pragma unroll
      for (int r = 0; r < 4; r++) s2[mt][r] = 0.f;
    }
    #pragma unroll
    for (int mt = 0; mt < 4; mt++) {
      #pragma unroll
      for (int nt = 0; nt < 4; nt++) {
        const int d = nt * 16 + l15;
        #pragma unroll
        for (int r = 0; r < 4; r++) {
          const int m = mrow0 + mt * 16 + lg * 4 + r;
          float v = (acc[mt][nt][r] + bv4[nt]) * QS;
          qb[((size_t)h * SL + m) * 64 + d] = f2bf(v);
          s2[mt][r] = fmaf(v, v, s2[mt][r]);
        }
      }
    }
    #pragma unroll
    for (int mt = 0; mt < 4; mt++)
      #pragma unroll
      for (int r = 0; r < 4; r++) {
        #pragma unroll
        for (int off = 1; off < 16; off <<= 1)
          s2[mt][r] += __shfl_xor(s2[mt][r], off, 64);
      }
    if (l15 == 0) {
      #pragma unroll
      for (int mt = 0; mt < 4; mt++)
        #pragma unroll
        for (int r = 0; r < 4; r++)
          qn2[(size_t)h * SL + mrow0 + mt * 16 + lg * 4 + r] = s2[mt][r];
    }
  } else if (secn == 1) {
    float s2[4][4];
    #pragma unroll
    for (int mt = 0; mt < 4; mt++) {
      #pragma unroll
      for (int r = 0; r < 4; r++) s2[mt][r] = 0.f;
    }
    #pragma unroll
    for (int mt = 0; mt < 4; mt++) {
      #pragma unroll
      for (int nt = 0; nt < 4; nt++) {
        const int d = nt * 16 + l15;
        #pragma unroll
        for (int r = 0; r < 4; r++) {
          const int m = mrow0 + mt * 16 + lg * 4 + r;
          float v = acc[mt][nt][r] + bv4[nt];
          kbo[((size_t)h * SL + m) * 64 + d] = f2bf(v);
          s2[mt][r] = fmaf(v, v, s2[mt][r]);
        }
      }
    }
    float rm = 0.f;
    #pragma unroll
    for (int mt = 0; mt < 4; mt++)
      #pragma unroll
      for (int r = 0; r < 4; r++) {
        #pragma unroll
        for (int off = 1; off < 16; off <<= 1)
          s2[mt][r] += __shfl_xor(s2[mt][r], off, 64);
        rm = fmaxf(rm, s2[mt][r]);
      }
    rm = fmaxf(rm, __shfl_xor(rm, 16, 64));
    rm = fmaxf(rm, __shfl_xor(rm, 32, 64));
    if (l == 0) atomicMax(kmx + h, __float_as_uint(rm));   // norm^2, >=0
  } else {
    #pragma unroll
    for (int mt = 0; mt < 4; mt++) {
      #pragma unroll
      for (int nt = 0; nt < 4; nt++) {
        const int d = nt * 16 + l15;
        u16x4 o;
        #pragma unroll
        for (int r = 0; r < 4; r++) o[r] = f2bf(acc[mt][nt][r] + bv4[nt]);
        *reinterpret_cast<u16x4*>(
            vtb + ((size_t)h * 64 + d) * SL + mrow0 + mt * 16 + lg * 4) = o;
      }
    }
  }
}

// 32x32 swapped attention body, KVBLK=32, fixed-bound softmax (-M via MFMA),
// row-sum via MFMA ones-trick. kfo/vfo are precomputed conflict-free offsets.
__device__ __forceinline__ void attn_body32f(
    const unsigned short* kb, const unsigned short* vb,
    const s16x8* qf, f32x16* ot, f32x16& lacc, s16x8 qm,
    const int* kfo, const int* vfo, s16x8 ones) {
  f32x16 st = (f32x16)0.f;
  __builtin_amdgcn_s_setprio(1);
  #pragma unroll
  for (int c = 0; c < 4; c++) {
    s16x8 kf = *reinterpret_cast<const s16x8*>(&kb[kfo[c]]);
    st = MF32(kf, qf[c], st);
  }
  st = MF32(ones, qm, st);
  __builtin_amdgcn_s_setprio(0);
  #pragma unroll
  for (int r = 0; r < 16; r++) st[r] = exp2f(st[r]);
  #pragma unroll
  for (int m = 0; m < 2; m++) {
    const int m0 = m * 8;
    unsigned w0, w1, w2, w3;
    asm("v_cvt_pk_bf16_f32 %0, %1, %2" : "=v"(w0) : "v"(st[m0 + 0]), "v"(st[m0 + 1]));
    asm("v_cvt_pk_bf16_f32 %0, %1, %2" : "=v"(w1) : "v"(st[m0 + 2]), "v"(st[m0 + 3]));
    asm("v_cvt_pk_bf16_f32 %0, %1, %2" : "=v"(w2) : "v"(st[m0 + 4]), "v"(st[m0 + 5]));
    asm("v_cvt_pk_bf16_f32 %0, %1, %2" : "=v"(w3) : "v"(st[m0 + 6]), "v"(st[m0 + 7]));
    asm volatile("v_permlane32_swap_b32 %0, %1" : "+v"(w0), "+v"(w2));
    asm volatile("v_permlane32_swap_b32 %0, %1" : "+v"(w1), "+v"(w3));
    u32x4 wv_;
    wv_[0] = w0; wv_[1] = w1; wv_[2] = w2; wv_[3] = w3;
    s16x8 pbf = *reinterpret_cast<s16x8*>(&wv_);
    __builtin_amdgcn_s_setprio(1);
    #pragma unroll
    for (int dt = 0; dt < 2; dt++) {
      s16x8 vf = *reinterpret_cast<const s16x8*>(&vb[vfo[m * 2 + dt]]);
      ot[dt] = MF32(vf, pbf, ot[dt]);
    }
    lacc = MF32(ones, pbf, lacc);
    __builtin_amdgcn_s_setprio(0);
  }
}

// Flash attention: 4 waves = 2 q-subtiles x 2 KV-halves; KVBLK=32; async dbuf
// with COUNTED vmcnt(4); conflict-free fused V tile (0 conflicts); fixed-bound
// softmax; in-WG merge of the two halves (overlay on dead staging LDS).
extern "C" __global__ __launch_bounds__(256) void k_attn(
    const unsigned short* __restrict__ qb, const unsigned short* __restrict__ kbi,
    const unsigned short* __restrict__ vt, const float* __restrict__ qn2,
    const unsigned* __restrict__ kmx, unsigned short* __restrict__ aout) {
  __shared__ alignas(16) unsigned char smem[32768];
  unsigned short* kst = (unsigned short*)smem;             // [4][2048] K staging
  unsigned short* vst = (unsigned short*)(smem + 16384);   // [4][2048] V staging
  const int t = threadIdx.x, w = t >> 6, l = t & 63;
  const int l31 = l & 31, s = l >> 5;
  const int half = w >> 1, qs = w & 1;
  const int bid = blockIdx.x;
  const int sid = (bid & 7) * 96 + (bid >> 3);   // XCD head-clustering
  const int h = sid >> 6, qt = sid & 63;
  const unsigned short* qh = qb + (size_t)h * SL * 64;
  const unsigned short* kh = kbi + ((size_t)h * SL + half * 2048) * 64;
  const unsigned short* vh = vt + (size_t)h * 64 * SL + half * 2048;
  const int q = qt * 64 + qs * 32 + l31;
  const float M = sqrtf(qn2[(size_t)h * SL + q] * __uint_as_float(kmx[h]));
  s16x8 qf[4];
  #pragma unroll
  for (int c = 0; c < 4; c++)
    qf[c] = *reinterpret_cast<const s16x8*>(qh + (size_t)q * 64 + c * 16 + s * 8);
  s16x8 ones;
  #pragma unroll
  for (int e = 0; e < 8; e++) ones[e] = (short)0x3F80;     // bf16 1.0
  s16x8 qm = (s16x8)0;
  if (s == 0) qm[0] = (short)f2bf(-M);                      // k-slot 0 holds -M(q)
  f32x16 ot[2];
  ot[0] = (f32x16)0.f;
  ot[1] = (f32x16)0.f;
  f32x16 lacc = (f32x16)0.f;
  // staging source offsets (pre-inverse-swizzled; LDS dest linear) — R10-verified
  int koff[2], voff[2];
  #pragma unroll
  for (int c = 0; c < 2; c++) {
    int i = (qs * 2 + c) * 64 + l;
    int row = i >> 3, sb = i & 7;
    int bp = sb ^ ((row ^ (row >> 3)) & 7);
    koff[c] = row * 64 + bp * 8;
    int d = row + 32 * (bp >> 2);
    voff[c] = d * SL + (bp & 3) * 8;
  }
  // fragment read offsets (conflict-free, R9/R10-verified)
  const int sr = (l31 ^ (l31 >> 3)) & 7;
  int kfo[4], vfo[4];
  #pragma unroll
  for (int c = 0; c < 4; c++) kfo[c] = (l31 << 6) + (((c * 2 + s) ^ sr) << 3);
  #pragma unroll
  for (int m = 0; m < 2; m++)
    #pragma unroll
    for (int dt = 0; dt < 2; dt++)
      vfo[m * 2 + dt] = (l31 << 6) + (((dt * 4 + m * 2 + s) ^ sr) << 3);

#define STAGE_KV(B, LB)                                                     \
  do {                                                                      \
    _Pragma("unroll")                                                       \
    for (int c = 0; c < 2; c++) {                                           \
      ASYNC16(kh + (size_t)(LB) * 64 + koff[c],                             \
              kst + (half * 2 + (B)) * 2048 + (qs * 2 + c) * 512);          \
      ASYNC16(vh + (LB) + voff[c],                                          \
              vst + (half * 2 + (B)) * 2048 + (qs * 2 + c) * 512);          \
    }                                                                       \
  } while (0)

  STAGE_KV(0, 0);
  #pragma unroll 1
  for (int lb = 0; lb < 2048; lb += 64) {
    STAGE_KV(1, lb + 32);
    asm volatile("s_waitcnt vmcnt(4)" ::: "memory");   // buf0's 4 done; buf1 in flight
    __builtin_amdgcn_s_barrier();
    attn_body32f(kst + (half * 2) * 2048, vst + (half * 2) * 2048,
                 qf, ot, lacc, qm, kfo, vfo, ones);
    if (lb + 64 < 2048) {
      STAGE_KV(0, lb + 64);
      asm volatile("s_waitcnt vmcnt(4)" ::: "memory"); // buf1's 4 done; buf0 in flight
    } else {
      asm volatile("s_waitcnt vmcnt(0)" ::: "memory"); // tail drain
    }
    __builtin_amdgcn_s_barrier();
    attn_body32f(kst + (half * 2 + 1) * 2048, vst + (half * 2 + 1) * 2048,
                 qf, ot, lacc, qm, kfo, vfo, ones);
  }
#undef STAGE_KV
  // merge the two halves (same M shift => plain adds); overlay staging LDS
  const float lsum = lacc[0];
  float* o_m = (float*)smem;                 // [2][32][68]
  float* l_m = (float*)(smem + 17408);       // [2][32]
  __syncthreads();
  if (half == 1) {
    #pragma unroll
    for (int dt = 0; dt < 2; dt++) {
      #pragma unroll
      for (int rq = 0; rq < 4; rq++) {
        f32x4 v;
        #pragma unroll
        for (int j = 0; j < 4; j++) v[j] = ot[dt][rq * 4 + j];
        *reinterpret_cast<f32x4*>(&o_m[(qs * 32 + l31) * 68 + dt * 32 + rq * 8 + s * 4]) = v;
      }
    }
    if (s == 0) l_m[qs * 32 + l31] = lsum;
  }
  __syncthreads();
  if (half == 0) {
    const float linv = 1.f / (lsum + l_m[qs * 32 + l31]);
    #pragma unroll
    for (int dt = 0; dt < 2; dt++) {
      #pragma unroll
      for (int rq = 0; rq < 4; rq++) {
        f32x4 vb_ = *reinterpret_cast<const f32x4*>(&o_m[(qs * 32 + l31) * 68 + dt * 32 + rq * 8 + s * 4]);
        u16x4 o;
        #pragma unroll
        for (int j = 0; j < 4; j++)
          o[j] = f2bf((ot[dt][rq * 4 + j] + vb_[j]) * linv);
        *reinterpret_cast<u16x4*>(aout + (size_t)q * DM + h * 64 + dt * 32 + rq * 8 + s * 4) = o;
      }
    }
  }
}

// ---- out-proj GEMM + bias + residual -> y (fp32), 64x64 tile (768 WGs: fills
// the GPU at 3 WG/CU; the 128x128 grid of 192 WGs underfilled — R8-R12 data) ----
__device__ __forceinline__ void gemm_body(
    const unsigned short* al, const unsigned short* bl, f32x4* acc,
    int wv, int l15, int lg) {
  #pragma unroll
  for (int kc = 0; kc < 2; kc++) {
    s16x8 af = *reinterpret_cast<const s16x8*>(&al[swz(wv * 16 + l15, kc * 32 + lg * 8)]);
    #pragma unroll
    for (int nt = 0; nt < 4; nt++) {
      s16x8 bfr = *reinterpret_cast<const s16x8*>(&bl[swz(nt * 16 + l15, kc * 32 + lg * 8)]);
      acc[nt] = __builtin_amdgcn_mfma_f32_16x16x32_bf16(af, bfr, acc[nt], 0, 0, 0);
    }
  }
}

extern "C" __global__ __launch_bounds__(256) void k_out(
    const unsigned short* __restrict__ abf, const unsigned short* __restrict__ wot,
    const float* __restrict__ bias, const float* __restrict__ x, float* __restrict__ y) {
  __shared__ alignas(16) unsigned short a_lds[2][4096];
  __shared__ alignas(16) unsigned short b_lds[2][4096];
  const int t = threadIdx.x, wv = t >> 6, l = t & 63;
  const int l15 = l & 15, lg = l >> 4;
  const int m0 = blockIdx.y * 64, n0 = blockIdx.x * 64;
  f32x4 acc[4];
  acc[0] = acc[1] = acc[2] = acc[3] = (f32x4)0.f;
  int soff[2];
  #pragma unroll
  for (int c = 0; c < 2; c++) {
    int idx = wv * 128 + c * 64 + l;
    int row = idx >> 3, bp = idx & 7;
    soff[c] = row * DM + (bp ^ (row & 7)) * 8;
  }
  const unsigned short* asrc = abf + (size_t)m0 * DM;
  const unsigned short* bsrc = wot + (size_t)n0 * DM;
  unsigned short* la = &a_lds[0][0];
  unsigned short* lb = &b_lds[0][0];

#define STAGE_AB(B, KK)                                              \
  do {                                                               \
    ASYNC16(asrc + (KK) + soff[0], la + (B)*4096 + wv * 1024);       \
    ASYNC16(asrc + (KK) + soff[1], la + (B)*4096 + wv * 1024 + 512); \
    ASYNC16(bsrc + (KK) + soff[0], lb + (B)*4096 + wv * 1024);       \
    ASYNC16(bsrc + (KK) + soff[1], lb + (B)*4096 + wv * 1024 + 512); \
  } while (0)

  STAGE_AB(0, 0);
  WAITB();
  for (int kk = 0; kk < DM; kk += 128) {
    STAGE_AB(1, kk + 64);
    gemm_body(&a_lds[0][0], &b_lds[0][0], acc, wv, l15, lg);
    WAITB();
    if (kk + 128 < DM) STAGE_AB(0, kk + 128);
    gemm_body(&a_lds[1][0], &b_lds[1][0], acc, wv, l15, lg);
    WAITB();
  }
#undef STAGE_AB
  const int mb = m0 + wv * 16 + lg * 4;
  #pragma unroll
  for (int nt = 0; nt < 4; nt++) {
    const int n = n0 + nt * 16 + l15;
    const float bv = bias[n];
    #pragma unroll
    for (int r = 0; r < 4; r++)
      y[(size_t)(mb + r) * DM + n] = acc[nt][r] + bv + x[(size_t)(mb + r) * DM + n];
  }
}

extern "C" __global__ __launch_bounds__(256) void k_ln(
    const float* __restrict__ y, const float* __restrict__ g, const float* __restrict__ b,
    float* __restrict__ out) {
  const int row = blockIdx.x, t = threadIdx.x;
  const float* yr = y + (size_t)row * DM;
  float v0 = yr[t], v1 = yr[t + 256], v2 = yr[t + 512];
  float sum = v0 + v1 + v2;
  float sq = v0 * v0 + v1 * v1 + v2 * v2;
  #pragma unroll
  for (int off = 1; off < 64; off <<= 1) {
    sum += __shfl_xor(sum, off, 64);
    sq += __shfl_xor(sq, off, 64);
  }
  __shared__ float ls[8];
  const int wv = t >> 6, l = t & 63;
  if (l == 0) { ls[wv] = sum; ls[4 + wv] = sq; }
  __syncthreads();
  sum = ls[0] + ls[1] + ls[2] + ls[3];
  sq = ls[4] + ls[5] + ls[6] + ls[7];
  const float mu = sum * (1.f / DM);
  const float rstd = rsqrtf(sq * (1.f / DM) - mu * mu + 1e-5f);
  out[(size_t)row * DM + t] = (v0 - mu) * rstd * g[t] + b[t];
  out[(size_t)row * DM + t + 256] = (v1 - mu) * rstd * g[t + 256] + b[t + 256];
  out[(size_t)row * DM + t + 512] = (v2 - mu) * rstd * g[t + 512] + b[t + 512];
}

extern "C" void kernel_launch(void* const* d_in, const int* in_sizes, int n_in,
                              void* d_out, int out_size, void* d_ws, size_t ws_size,
                              hipStream_t stream) {
  (void)in_sizes; (void)n_in; (void)out_size; (void)ws_size;
  const float* x = (const float*)d_in[0];
  const float* Wa = (const float*)d_in[1];
  const float* ba = (const float*)d_in[2];
  const float* Wo = (const float*)d_in[3];
  const float* bo = (const float*)d_in[4];
  const float* lng = (const float*)d_in[5];
  const float* lnb = (const float*)d_in[6];
  float* out = (float*)d_out;

  unsigned short* ws16 = (unsigned short*)d_ws;
  unsigned short* xbf = ws16;                 // 4096x768
  unsigned short* wat = xbf + 3145728;        // 2304x768 (W_attn^T)
  unsigned short* wot = wat + 1769472;        // 768x768  (W_out^T)
  unsigned short* qbf = wot + 589824;         // [12][4096][64]
  unsigned short* kbf = qbf + 3145728;        // [12][4096][64]
  unsigned short* vtb = kbf + 3145728;        // [12][64][4096]
  unsigned short* aob = vtb + 3145728;        // 4096x768 attn out
  float* ybuf = (float*)(aob + 3145728);      // 4096x768 fp32
  float* qn2 = ybuf + 3145728;                // [12][4096] |q|^2
  unsigned* kmx = (unsigned*)(qn2 + 49152);   // [12] max |k|^2 (as uint)

  k_prep<<<3648, 256, 0, stream>>>(x, Wa, Wo, xbf, wat, wot, kmx);
  k_qkv<<<dim3(18, 32), 256, 0, stream>>>(xbf, wat, ba, qbf, kbf, vtb, qn2, kmx);
  k_attn<<<768, 256, 0, stream>>>(qbf, kbf, vtb, qn2, kmx, aob);
  k_out<<<dim3(12, 64), 256, 0, stream>>>(aob, wot, bo, x, ybuf);
  k_ln<<<4096, 256, 0, stream>>>(ybuf, lng, lnb, out);
}